// Round 1
// baseline (860.838 us; speedup 1.0000x reference)
//
#include <hip/hip_runtime.h>
#include <stdint.h>

#define D_MODEL 2048
#define N_ROOMS 128
#define BATCH   128
#define SEQ     512
#define NN      (N_ROOMS * N_ROOMS)   // 16384

typedef short bf16x8 __attribute__((ext_vector_type(8)));
typedef float f32x4  __attribute__((ext_vector_type(4)));

__device__ __forceinline__ unsigned short f2bf(float f) {
    union { float f; uint32_t u; } c; c.f = f;
    uint32_t u = c.u;
    uint32_t r = (u + 0x7fffu + ((u >> 16) & 1u)) >> 16;  // RNE
    return (unsigned short)r;
}
__device__ __forceinline__ float bf2f(unsigned short h) {
    union { uint32_t u; float f; } c; c.u = ((uint32_t)h) << 16;
    return c.f;
}

// ---------------------------------------------------------------- mean over S
// grid 1024 = B(128) x sc(4) x dc(2); 256 thr; each thread one float4 of d,
// 128 s-steps. Writes partial sums part[sc][b][d].
__global__ void k_mean_partial(const float* __restrict__ x, float* __restrict__ part) {
    int bx = blockIdx.x;
    int b = bx >> 3, rem = bx & 7;
    int sc = rem >> 1, dc = rem & 1;
    int d = dc * 1024 + threadIdx.x * 4;
    const float* p = x + ((size_t)(b * SEQ + sc * 128)) * D_MODEL + d;
    float ax = 0.f, ay = 0.f, az = 0.f, aw = 0.f;
    #pragma unroll 4
    for (int s = 0; s < 128; ++s) {
        float4 v = *(const float4*)p;
        ax += v.x; ay += v.y; az += v.z; aw += v.w;
        p += D_MODEL;
    }
    float4 o = {ax, ay, az, aw};
    *(float4*)(part + ((size_t)(sc * BATCH + b)) * D_MODEL + d) = o;
}

// ---------------------------------------------------- combine mean + hi/lo bf16
__global__ void k_mean_combine(const float* __restrict__ part, float* __restrict__ mean,
                               unsigned short* __restrict__ mhi, unsigned short* __restrict__ mlo) {
    int i = (blockIdx.x * 256 + threadIdx.x) * 4;   // 256 blocks -> covers B*D
    float4 s = {0.f, 0.f, 0.f, 0.f};
    #pragma unroll
    for (int sc = 0; sc < 4; ++sc) {
        float4 v = *(const float4*)(part + (size_t)sc * BATCH * D_MODEL + i);
        s.x += v.x; s.y += v.y; s.z += v.z; s.w += v.w;
    }
    const float inv = 1.0f / (float)SEQ;
    s.x *= inv; s.y *= inv; s.z *= inv; s.w *= inv;
    *(float4*)(mean + i) = s;
    unsigned short h0 = f2bf(s.x), h1 = f2bf(s.y), h2 = f2bf(s.z), h3 = f2bf(s.w);
    ushort4 hv = {h0, h1, h2, h3};
    ushort4 lv = {f2bf(s.x - bf2f(h0)), f2bf(s.y - bf2f(h1)),
                  f2bf(s.z - bf2f(h2)), f2bf(s.w - bf2f(h3))};
    *(ushort4*)(mhi + i) = hv;
    *(ushort4*)(mlo + i) = lv;
}

// -------------------------------------------- context GEMM (compensated bf16)
// C[b][d] = sum_k mean[b][k] * Wc[d][k];  M=128, N=2048, K=2048.
// tile 128x64, BK=64, K-split 8 -> grid 256. Partials to ctx_part[ks][b][d].
__launch_bounds__(256)
__global__ void k_ctx_gemm(const unsigned short* __restrict__ mhi,
                           const unsigned short* __restrict__ mlo,
                           const float* __restrict__ Wc,
                           float* __restrict__ ctx_part) {
    __shared__ short Ah[128 * 72];
    __shared__ short Al[128 * 72];
    __shared__ short Bh[64 * 72];
    __shared__ short Bl[64 * 72];
    int bx = blockIdx.x;
    int nt = bx & 31, ks = bx >> 5;
    int n0 = nt * 64;
    int k0 = ks * 256;
    int tid = threadIdx.x, lane = tid & 63, w = tid >> 6;
    int mbase = w * 32;
    f32x4 acc[2][4] = {};
    for (int kt = 0; kt < 4; ++kt) {
        int kb = k0 + kt * 64;
        __syncthreads();
        #pragma unroll
        for (int i = 0; i < 4; ++i) {            // A: 128 rows x 64 bf16 (hi+lo)
            int u = tid + 256 * i;
            int row = u >> 3, c = u & 7;
            *(int4*)&Ah[row * 72 + c * 8] = *(const int4*)(mhi + (size_t)row * D_MODEL + kb + c * 8);
            *(int4*)&Al[row * 72 + c * 8] = *(const int4*)(mlo + (size_t)row * D_MODEL + kb + c * 8);
        }
        #pragma unroll
        for (int i = 0; i < 4; ++i) {            // B: 64 rows x 64 fp32 -> hi/lo
            int u = tid + 256 * i;
            int row = u >> 4, c = u & 15;
            float4 v = *(const float4*)(Wc + (size_t)(n0 + row) * D_MODEL + kb + c * 4);
            unsigned short h0 = f2bf(v.x), h1 = f2bf(v.y), h2 = f2bf(v.z), h3 = f2bf(v.w);
            ushort4 hv = {h0, h1, h2, h3};
            ushort4 lv = {f2bf(v.x - bf2f(h0)), f2bf(v.y - bf2f(h1)),
                          f2bf(v.z - bf2f(h2)), f2bf(v.w - bf2f(h3))};
            *(ushort4*)&Bh[row * 72 + c * 4] = hv;
            *(ushort4*)&Bl[row * 72 + c * 4] = lv;
        }
        __syncthreads();
        #pragma unroll
        for (int kk = 0; kk < 64; kk += 32) {
            int ko = kk + (lane >> 4) * 8;
            int mr = mbase + (lane & 15);
            bf16x8 ah0 = *(const bf16x8*)&Ah[mr * 72 + ko];
            bf16x8 ah1 = *(const bf16x8*)&Ah[(mr + 16) * 72 + ko];
            bf16x8 al0 = *(const bf16x8*)&Al[mr * 72 + ko];
            bf16x8 al1 = *(const bf16x8*)&Al[(mr + 16) * 72 + ko];
            #pragma unroll
            for (int ni = 0; ni < 4; ++ni) {
                int nr = ni * 16 + (lane & 15);
                bf16x8 bh = *(const bf16x8*)&Bh[nr * 72 + ko];
                bf16x8 bl = *(const bf16x8*)&Bl[nr * 72 + ko];
                acc[0][ni] = __builtin_amdgcn_mfma_f32_16x16x32_bf16(ah0, bh, acc[0][ni], 0, 0, 0);
                acc[0][ni] = __builtin_amdgcn_mfma_f32_16x16x32_bf16(al0, bh, acc[0][ni], 0, 0, 0);
                acc[0][ni] = __builtin_amdgcn_mfma_f32_16x16x32_bf16(ah0, bl, acc[0][ni], 0, 0, 0);
                acc[1][ni] = __builtin_amdgcn_mfma_f32_16x16x32_bf16(ah1, bh, acc[1][ni], 0, 0, 0);
                acc[1][ni] = __builtin_amdgcn_mfma_f32_16x16x32_bf16(al1, bh, acc[1][ni], 0, 0, 0);
                acc[1][ni] = __builtin_amdgcn_mfma_f32_16x16x32_bf16(ah1, bl, acc[1][ni], 0, 0, 0);
            }
        }
    }
    int col = lane & 15, quad = lane >> 4;
    #pragma unroll
    for (int mi = 0; mi < 2; ++mi)
        #pragma unroll
        for (int ni = 0; ni < 4; ++ni)
            #pragma unroll
            for (int r = 0; r < 4; ++r) {
                int m = mbase + mi * 16 + quad * 4 + r;    // b
                int n = n0 + ni * 16 + col;                // d
                ctx_part[((size_t)(ks * BATCH + m)) * D_MODEL + n] = acc[mi][ni][r];
            }
}

// ------------------------------------------ finalize context (+bc, emit bf16)
__global__ void k_ctx_finalize(const float* __restrict__ ctx_part, const float* __restrict__ bc,
                               float* __restrict__ ctx, unsigned short* __restrict__ ctxb) {
    int i = (blockIdx.x * 256 + threadIdx.x) * 4;
    float4 s = {0.f, 0.f, 0.f, 0.f};
    #pragma unroll
    for (int ks = 0; ks < 8; ++ks) {
        float4 v = *(const float4*)(ctx_part + (size_t)ks * BATCH * D_MODEL + i);
        s.x += v.x; s.y += v.y; s.z += v.z; s.w += v.w;
    }
    int d = i & (D_MODEL - 1);
    float4 bias = *(const float4*)(bc + d);
    s.x += bias.x; s.y += bias.y; s.z += bias.z; s.w += bias.w;
    *(float4*)(ctx + i) = s;
    ushort4 hv = {f2bf(s.x), f2bf(s.y), f2bf(s.z), f2bf(s.w)};
    *(ushort4*)(ctxb + i) = hv;
}

// --------------------------------------------------- raw scores (fp32, small)
// raw[b][n] = dot(ctx[b], room[n]); grid 64 = bg(8) x ng(8), 16x16 tile.
__global__ void k_raw(const float* __restrict__ ctx, const float* __restrict__ room,
                      float* __restrict__ raw) {
    __shared__ float ct[16][132];
    __shared__ float rt[16][132];
    int bg = blockIdx.x >> 3, ng = blockIdx.x & 7;
    int tid = threadIdx.x;
    int bi = tid >> 4, ni = tid & 15;
    float acc = 0.f;
    for (int kc = 0; kc < D_MODEL; kc += 128) {
        __syncthreads();
        #pragma unroll
        for (int i = 0; i < 2; ++i) {
            int u = tid + 256 * i;
            int row = u >> 5, c = u & 31;
            *(float4*)&ct[row][c * 4] = *(const float4*)(ctx + (size_t)(bg * 16 + row) * D_MODEL + kc + c * 4);
            *(float4*)&rt[row][c * 4] = *(const float4*)(room + (size_t)(ng * 16 + row) * D_MODEL + kc + c * 4);
        }
        __syncthreads();
        #pragma unroll 8
        for (int c = 0; c < 32; ++c) {
            float4 a = *(const float4*)&ct[bi][c * 4];
            float4 r = *(const float4*)&rt[ni][c * 4];
            acc += a.x * r.x + a.y * r.y + a.z * r.z + a.w * r.w;
        }
    }
    raw[(bg * 16 + bi) * N_ROOMS + ng * 16 + ni] = acc;
}

// --------------------------------------------------- warp GEMM (plain bf16)
// warp[b][r] = sum_k ctx[b][k]*Ww[r][k]; M=128, N=16384, K=2048.
// tile 128x64, BK=64, K-split 2 -> grid 512; partials to wp[ks][b][r].
__launch_bounds__(256)
__global__ void k_warp_gemm(const unsigned short* __restrict__ ctxb,
                            const float* __restrict__ Ww,
                            float* __restrict__ wp) {
    __shared__ short A[128 * 72];
    __shared__ short Bt[64 * 72];
    int bx = blockIdx.x;
    int nt = bx & 255, ks = bx >> 8;
    int n0 = nt * 64;
    int k0 = ks * 1024;
    int tid = threadIdx.x, lane = tid & 63, w = tid >> 6;
    int mbase = w * 32;
    f32x4 acc[2][4] = {};
    for (int kt = 0; kt < 16; ++kt) {
        int kb = k0 + kt * 64;
        __syncthreads();
        #pragma unroll
        for (int i = 0; i < 4; ++i) {            // A: 128 x 64 bf16 from ctxb
            int u = tid + 256 * i;
            int row = u >> 3, c = u & 7;
            *(int4*)&A[row * 72 + c * 8] = *(const int4*)(ctxb + (size_t)row * D_MODEL + kb + c * 8);
        }
        #pragma unroll
        for (int i = 0; i < 4; ++i) {            // B: 64 x 64 fp32 -> bf16
            int u = tid + 256 * i;
            int row = u >> 4, c = u & 15;
            float4 v = *(const float4*)(Ww + (size_t)(n0 + row) * D_MODEL + kb + c * 4);
            ushort4 hv = {f2bf(v.x), f2bf(v.y), f2bf(v.z), f2bf(v.w)};
            *(ushort4*)&Bt[row * 72 + c * 4] = hv;
        }
        __syncthreads();
        #pragma unroll
        for (int kk = 0; kk < 64; kk += 32) {
            int ko = kk + (lane >> 4) * 8;
            int mr = mbase + (lane & 15);
            bf16x8 a0 = *(const bf16x8*)&A[mr * 72 + ko];
            bf16x8 a1 = *(const bf16x8*)&A[(mr + 16) * 72 + ko];
            #pragma unroll
            for (int ni = 0; ni < 4; ++ni) {
                bf16x8 bfr = *(const bf16x8*)&Bt[(ni * 16 + (lane & 15)) * 72 + ko];
                acc[0][ni] = __builtin_amdgcn_mfma_f32_16x16x32_bf16(a0, bfr, acc[0][ni], 0, 0, 0);
                acc[1][ni] = __builtin_amdgcn_mfma_f32_16x16x32_bf16(a1, bfr, acc[1][ni], 0, 0, 0);
            }
        }
    }
    int col = lane & 15, quad = lane >> 4;
    #pragma unroll
    for (int mi = 0; mi < 2; ++mi)
        #pragma unroll
        for (int ni = 0; ni < 4; ++ni)
            #pragma unroll
            for (int r = 0; r < 4; ++r) {
                int m = mbase + mi * 16 + quad * 4 + r;    // b
                int n = n0 + ni * 16 + col;                // r-col
                wp[(size_t)ks * BATCH * NN + (size_t)m * NN + n] = acc[mi][ni][r];
            }
}

// ----------------------- epilogue: softmax(adj + 0.1*(warp+bw)) . raw -> sigmoid
// one wave per (b,i) row; 2 j's per lane.
__global__ void k_epilogue(const float* __restrict__ wp, const float* __restrict__ bw,
                           const float* __restrict__ adj, const float* __restrict__ raw,
                           float* __restrict__ out) {
    int tid = threadIdx.x, lane = tid & 63, w = tid >> 6;
    int row = blockIdx.x * 4 + w;               // b*128 + i
    int b = row >> 7, i = row & 127;
    int j0 = lane, j1 = lane + 64;
    size_t base = (size_t)row * 128;
    float w0 = wp[base + j0] + wp[(size_t)BATCH * NN + base + j0];
    float w1 = wp[base + j1] + wp[(size_t)BATCH * NN + base + j1];
    float l0 = adj[i * 128 + j0] + 0.1f * (w0 + bw[i * 128 + j0]);
    float l1 = adj[i * 128 + j1] + 0.1f * (w1 + bw[i * 128 + j1]);
    float m = fmaxf(l0, l1);
    #pragma unroll
    for (int off = 32; off; off >>= 1) m = fmaxf(m, __shfl_xor(m, off));
    float p0 = __expf(l0 - m), p1 = __expf(l1 - m);
    float s = p0 + p1;
    float t = p0 * raw[b * 128 + j0] + p1 * raw[b * 128 + j1];
    #pragma unroll
    for (int off = 32; off; off >>= 1) { s += __shfl_xor(s, off); t += __shfl_xor(t, off); }
    if (lane == 0) out[row] = 1.0f / (1.0f + __expf(-(t / s)));
}

extern "C" void kernel_launch(void* const* d_in, const int* in_sizes, int n_in,
                              void* d_out, int out_size, void* d_ws, size_t ws_size,
                              hipStream_t stream) {
    (void)in_sizes; (void)n_in; (void)out_size; (void)ws_size;
    const float* x    = (const float*)d_in[0];
    const float* room = (const float*)d_in[1];
    const float* Wc   = (const float*)d_in[2];
    const float* bc   = (const float*)d_in[3];
    const float* Ww   = (const float*)d_in[4];
    const float* bw   = (const float*)d_in[5];
    const float* adj  = (const float*)d_in[6];
    float* out = (float*)d_out;
    char* ws = (char*)d_ws;
    const size_t MB = 1u << 20;
    float*          part     = (float*)(ws + 0);                      // 4 MB
    float*          mean     = (float*)(ws + 4 * MB);                 // 1 MB
    unsigned short* mhi      = (unsigned short*)(ws + 5 * MB);        // 512 KB
    unsigned short* mlo      = (unsigned short*)(ws + 5 * MB + 512 * 1024);
    float*          ctx_part = (float*)(ws + 6 * MB);                 // 8 MB
    float*          ctx      = (float*)(ws + 14 * MB);                // 1 MB
    unsigned short* ctxb     = (unsigned short*)(ws + 15 * MB);       // 512 KB
    float*          raw      = (float*)(ws + 15 * MB + 512 * 1024);   // 64 KB
    float*          wp       = (float*)(ws + 16 * MB);                // 16 MB

    hipLaunchKernelGGL(k_mean_partial, dim3(1024), dim3(256), 0, stream, x, part);
    hipLaunchKernelGGL(k_mean_combine, dim3(256), dim3(256), 0, stream, part, mean, mhi, mlo);
    hipLaunchKernelGGL(k_ctx_gemm, dim3(256), dim3(256), 0, stream, mhi, mlo, Wc, ctx_part);
    hipLaunchKernelGGL(k_ctx_finalize, dim3(256), dim3(256), 0, stream, ctx_part, bc, ctx, ctxb);
    hipLaunchKernelGGL(k_raw, dim3(64), dim3(256), 0, stream, ctx, room, raw);
    hipLaunchKernelGGL(k_warp_gemm, dim3(512), dim3(256), 0, stream, ctxb, Ww, wp);
    hipLaunchKernelGGL(k_epilogue, dim3(4096), dim3(256), 0, stream, wp, bw, adj, raw, out);
}

// Round 2
// 840.296 us; speedup vs baseline: 1.0244x; 1.0244x over previous
//
#include <hip/hip_runtime.h>
#include <stdint.h>

#define D_MODEL 2048
#define N_ROOMS 128
#define BATCH   128
#define SEQ     512
#define NN      (N_ROOMS * N_ROOMS)   // 16384
#define NCOL    (NN + N_ROOMS)        // 16512: warp cols + raw cols

typedef short bf16x8 __attribute__((ext_vector_type(8)));
typedef float f32x4  __attribute__((ext_vector_type(4)));

__device__ __forceinline__ unsigned short f2bf(float f) {
    union { float f; uint32_t u; } c; c.f = f;
    uint32_t u = c.u;
    uint32_t r = (u + 0x7fffu + ((u >> 16) & 1u)) >> 16;  // RNE
    return (unsigned short)r;
}

// ---------------------------------------------------------------- mean over S
// grid 2048 = B(128) x sc(8) x dc(2); 256 thr; each thread one float4 of d,
// 64 s-steps. Writes partial sums part[sc][b][d].
__global__ void k_mean_partial(const float* __restrict__ x, float* __restrict__ part) {
    int bx = blockIdx.x;
    int b = bx >> 4, rem = bx & 15;
    int sc = rem >> 1, dc = rem & 1;
    int d = dc * 1024 + threadIdx.x * 4;
    const float* p = x + ((size_t)(b * SEQ + sc * 64)) * D_MODEL + d;
    float ax = 0.f, ay = 0.f, az = 0.f, aw = 0.f;
    #pragma unroll 8
    for (int s = 0; s < 64; ++s) {
        float4 v = *(const float4*)p;
        ax += v.x; ay += v.y; az += v.z; aw += v.w;
        p += D_MODEL;
    }
    float4 o = {ax, ay, az, aw};
    *(float4*)(part + ((size_t)(sc * BATCH + b)) * D_MODEL + d) = o;
}

// ------------------------------------------------- combine mean -> bf16 only
__global__ void k_mean_combine(const float* __restrict__ part,
                               unsigned short* __restrict__ meanb) {
    int i = (blockIdx.x * 256 + threadIdx.x) * 4;   // 256 blocks covers B*D
    float4 s = {0.f, 0.f, 0.f, 0.f};
    #pragma unroll
    for (int sc = 0; sc < 8; ++sc) {
        float4 v = *(const float4*)(part + (size_t)sc * BATCH * D_MODEL + i);
        s.x += v.x; s.y += v.y; s.z += v.z; s.w += v.w;
    }
    const float inv = 1.0f / (float)SEQ;
    ushort4 hv = {f2bf(s.x * inv), f2bf(s.y * inv), f2bf(s.z * inv), f2bf(s.w * inv)};
    *(ushort4*)(meanb + i) = hv;
}

// ---------------------------------------------------- context GEMM (bf16)
// C[b][d] = sum_k mean[b][k] * Wc[d][k];  M=128, N=2048, K=2048.
// tile 128x64, BK=64, K-split 8 -> grid 256. Partials to ctx_part[ks][b][d].
__launch_bounds__(256)
__global__ void k_ctx_gemm(const unsigned short* __restrict__ meanb,
                           const float* __restrict__ Wc,
                           float* __restrict__ ctx_part) {
    __shared__ short A[128 * 72];
    __shared__ short Bt[64 * 72];
    int bx = blockIdx.x;
    int nt = bx & 31, ks = bx >> 5;
    int n0 = nt * 64;
    int k0 = ks * 256;
    int tid = threadIdx.x, lane = tid & 63, w = tid >> 6;
    int mbase = w * 32;
    f32x4 acc[2][4] = {};
    for (int kt = 0; kt < 4; ++kt) {
        int kb = k0 + kt * 64;
        __syncthreads();
        #pragma unroll
        for (int i = 0; i < 4; ++i) {            // A: 128 rows x 64 bf16
            int u = tid + 256 * i;
            int row = u >> 3, c = u & 7;
            *(int4*)&A[row * 72 + c * 8] = *(const int4*)(meanb + (size_t)row * D_MODEL + kb + c * 8);
        }
        #pragma unroll
        for (int i = 0; i < 4; ++i) {            // B: 64 rows x 64 fp32 -> bf16
            int u = tid + 256 * i;
            int row = u >> 4, c = u & 15;
            float4 v = *(const float4*)(Wc + (size_t)(n0 + row) * D_MODEL + kb + c * 4);
            ushort4 hv = {f2bf(v.x), f2bf(v.y), f2bf(v.z), f2bf(v.w)};
            *(ushort4*)&Bt[row * 72 + c * 4] = hv;
        }
        __syncthreads();
        #pragma unroll
        for (int kk = 0; kk < 64; kk += 32) {
            int ko = kk + (lane >> 4) * 8;
            int mr = mbase + (lane & 15);
            bf16x8 a0 = *(const bf16x8*)&A[mr * 72 + ko];
            bf16x8 a1 = *(const bf16x8*)&A[(mr + 16) * 72 + ko];
            #pragma unroll
            for (int ni = 0; ni < 4; ++ni) {
                bf16x8 bfr = *(const bf16x8*)&Bt[(ni * 16 + (lane & 15)) * 72 + ko];
                acc[0][ni] = __builtin_amdgcn_mfma_f32_16x16x32_bf16(a0, bfr, acc[0][ni], 0, 0, 0);
                acc[1][ni] = __builtin_amdgcn_mfma_f32_16x16x32_bf16(a1, bfr, acc[1][ni], 0, 0, 0);
            }
        }
    }
    int col = lane & 15, quad = lane >> 4;
    #pragma unroll
    for (int mi = 0; mi < 2; ++mi)
        #pragma unroll
        for (int ni = 0; ni < 4; ++ni)
            #pragma unroll
            for (int r = 0; r < 4; ++r) {
                int m = mbase + mi * 16 + quad * 4 + r;    // b
                int n = n0 + ni * 16 + col;                // d
                ctx_part[((size_t)(ks * BATCH + m)) * D_MODEL + n] = acc[mi][ni][r];
            }
}

// -------------------------------------- finalize context (+bc) -> bf16 only
__global__ void k_ctx_finalize(const float* __restrict__ ctx_part, const float* __restrict__ bc,
                               unsigned short* __restrict__ ctxb) {
    int i = (blockIdx.x * 256 + threadIdx.x) * 4;
    float4 s = {0.f, 0.f, 0.f, 0.f};
    #pragma unroll
    for (int ks = 0; ks < 8; ++ks) {
        float4 v = *(const float4*)(ctx_part + (size_t)ks * BATCH * D_MODEL + i);
        s.x += v.x; s.y += v.y; s.z += v.z; s.w += v.w;
    }
    int d = i & (D_MODEL - 1);
    float4 bias = *(const float4*)(bc + d);
    ushort4 hv = {f2bf(s.x + bias.x), f2bf(s.y + bias.y), f2bf(s.z + bias.z), f2bf(s.w + bias.w)};
    *(ushort4*)(ctxb + i) = hv;
}

// ------------------------------------- warp+raw GEMM (bf16), fused N-domain
// cols [0,16384): warp[b][r] = sum_k ctx[b][k]*Ww[r][k]
// cols [16384,16512): raw[b][n] = sum_k ctx[b][k]*room[n][k]
// M=128, N=16512, K=2048. tile 128x64, BK=64, K-split 2 -> grid 516.
// Partials to wp[ks][b][16512].
__launch_bounds__(256)
__global__ void k_warp_gemm(const unsigned short* __restrict__ ctxb,
                            const float* __restrict__ Ww,
                            const float* __restrict__ room,
                            float* __restrict__ wp) {
    __shared__ short A[128 * 72];
    __shared__ short Bt[64 * 72];
    int bx = blockIdx.x;
    int nt = bx % 258, ks = bx / 258;
    int n0 = nt * 64;
    int k0 = ks * 1024;
    // tiles 0..255 -> Ww rows; tiles 256..257 -> room rows (16384/64==256 exact)
    const float* Bsrc = (nt < 256) ? (Ww + (size_t)n0 * D_MODEL)
                                   : (room + (size_t)(n0 - NN) * D_MODEL);
    int tid = threadIdx.x, lane = tid & 63, w = tid >> 6;
    int mbase = w * 32;
    f32x4 acc[2][4] = {};
    for (int kt = 0; kt < 16; ++kt) {
        int kb = k0 + kt * 64;
        __syncthreads();
        #pragma unroll
        for (int i = 0; i < 4; ++i) {            // A: 128 x 64 bf16 from ctxb
            int u = tid + 256 * i;
            int row = u >> 3, c = u & 7;
            *(int4*)&A[row * 72 + c * 8] = *(const int4*)(ctxb + (size_t)row * D_MODEL + kb + c * 8);
        }
        #pragma unroll
        for (int i = 0; i < 4; ++i) {            // B: 64 x 64 fp32 -> bf16
            int u = tid + 256 * i;
            int row = u >> 4, c = u & 15;
            float4 v = *(const float4*)(Bsrc + (size_t)row * D_MODEL + kb + c * 4);
            ushort4 hv = {f2bf(v.x), f2bf(v.y), f2bf(v.z), f2bf(v.w)};
            *(ushort4*)&Bt[row * 72 + c * 4] = hv;
        }
        __syncthreads();
        #pragma unroll
        for (int kk = 0; kk < 64; kk += 32) {
            int ko = kk + (lane >> 4) * 8;
            int mr = mbase + (lane & 15);
            bf16x8 a0 = *(const bf16x8*)&A[mr * 72 + ko];
            bf16x8 a1 = *(const bf16x8*)&A[(mr + 16) * 72 + ko];
            #pragma unroll
            for (int ni = 0; ni < 4; ++ni) {
                bf16x8 bfr = *(const bf16x8*)&Bt[(ni * 16 + (lane & 15)) * 72 + ko];
                acc[0][ni] = __builtin_amdgcn_mfma_f32_16x16x32_bf16(a0, bfr, acc[0][ni], 0, 0, 0);
                acc[1][ni] = __builtin_amdgcn_mfma_f32_16x16x32_bf16(a1, bfr, acc[1][ni], 0, 0, 0);
            }
        }
    }
    int col = lane & 15, quad = lane >> 4;
    #pragma unroll
    for (int mi = 0; mi < 2; ++mi)
        #pragma unroll
        for (int ni = 0; ni < 4; ++ni)
            #pragma unroll
            for (int r = 0; r < 4; ++r) {
                int m = mbase + mi * 16 + quad * 4 + r;    // b
                int n = n0 + ni * 16 + col;
                wp[((size_t)(ks * BATCH + m)) * NCOL + n] = acc[mi][ni][r];
            }
}

// ----------------- epilogue: softmax(adj + 0.1*(warp+bw)) . raw -> sigmoid
// one wave per (b,i) row; 2 j's per lane. K-split partials summed here.
__global__ void k_epilogue(const float* __restrict__ wp, const float* __restrict__ bw,
                           const float* __restrict__ adj, float* __restrict__ out) {
    int tid = threadIdx.x, lane = tid & 63, w = tid >> 6;
    int row = blockIdx.x * 4 + w;               // b*128 + i
    int b = row >> 7, i = row & 127;
    int j0 = lane, j1 = lane + 64;
    size_t b0 = (size_t)b * NCOL;
    size_t b1 = (size_t)(BATCH + b) * NCOL;
    int off = i * 128;
    float w0 = wp[b0 + off + j0] + wp[b1 + off + j0];
    float w1 = wp[b0 + off + j1] + wp[b1 + off + j1];
    float r0 = wp[b0 + NN + j0] + wp[b1 + NN + j0];
    float r1 = wp[b0 + NN + j1] + wp[b1 + NN + j1];
    float l0 = adj[off + j0] + 0.1f * (w0 + bw[off + j0]);
    float l1 = adj[off + j1] + 0.1f * (w1 + bw[off + j1]);
    float m = fmaxf(l0, l1);
    #pragma unroll
    for (int o = 32; o; o >>= 1) m = fmaxf(m, __shfl_xor(m, o));
    float p0 = __expf(l0 - m), p1 = __expf(l1 - m);
    float s = p0 + p1;
    float t = p0 * r0 + p1 * r1;
    #pragma unroll
    for (int o = 32; o; o >>= 1) { s += __shfl_xor(s, o); t += __shfl_xor(t, o); }
    if (lane == 0) out[row] = 1.0f / (1.0f + __expf(-(t / s)));
}

extern "C" void kernel_launch(void* const* d_in, const int* in_sizes, int n_in,
                              void* d_out, int out_size, void* d_ws, size_t ws_size,
                              hipStream_t stream) {
    (void)in_sizes; (void)n_in; (void)out_size; (void)ws_size;
    const float* x    = (const float*)d_in[0];
    const float* room = (const float*)d_in[1];
    const float* Wc   = (const float*)d_in[2];
    const float* bc   = (const float*)d_in[3];
    const float* Ww   = (const float*)d_in[4];
    const float* bw   = (const float*)d_in[5];
    const float* adj  = (const float*)d_in[6];
    float* out = (float*)d_out;
    char* ws = (char*)d_ws;
    const size_t MB = 1u << 20;
    float*          part     = (float*)(ws + 0);                      // 8 MB
    unsigned short* meanb    = (unsigned short*)(ws + 8 * MB);        // 512 KB
    float*          ctx_part = (float*)(ws + 9 * MB);                 // 8 MB
    unsigned short* ctxb     = (unsigned short*)(ws + 17 * MB);       // 512 KB
    float*          wp       = (float*)(ws + 18 * MB);                // ~16.2 MB

    hipLaunchKernelGGL(k_mean_partial, dim3(2048), dim3(256), 0, stream, x, part);
    hipLaunchKernelGGL(k_mean_combine, dim3(256), dim3(256), 0, stream, part, meanb);
    hipLaunchKernelGGL(k_ctx_gemm, dim3(256), dim3(256), 0, stream, meanb, Wc, ctx_part);
    hipLaunchKernelGGL(k_ctx_finalize, dim3(256), dim3(256), 0, stream, ctx_part, bc, ctxb);
    hipLaunchKernelGGL(k_warp_gemm, dim3(516), dim3(256), 0, stream, ctxb, Ww, room, wp);
    hipLaunchKernelGGL(k_epilogue, dim3(4096), dim3(256), 0, stream, wp, bw, adj, out);
}